// Round 3
// baseline (1337.348 us; speedup 1.0000x reference)
//
#include <hip/hip_runtime.h>

typedef unsigned short u16;
typedef __bf16 bf16x8 __attribute__((ext_vector_type(8)));
typedef float f32x4 __attribute__((ext_vector_type(4)));

#define HDIM 1024
#define VDIM 32000
#define NEXP 8
#define NTOK 2048
#define LSCALE 0.25f

__device__ __forceinline__ float bf2f(u16 v) {
  union { unsigned u; float f; } x; x.u = ((unsigned)v) << 16; return x.f;
}
__device__ __forceinline__ u16 f2bf(float f) {
  union { float f; unsigned u; } x; x.f = f;
  return (u16)((x.u + 0x7fffu + ((x.u >> 16) & 1u)) >> 16);
}
// dual-dtype scalar load (if/else so only one path's load executes)
__device__ __forceinline__ float lde(const void* p, size_t i, int isf32) {
  if (isf32) return ((const float*)p)[i];
  else       return bf2f(((const u16*)p)[i]);
}

// ---------------------------------------------------------------------------
// Dtype detector: sample u16s at even indices of `embedding`. For bf16 data
// these are real bf16 values of N(0,0.02) -> exponent in [87,127] nearly
// always. For fp32 data they are mantissa low-halves -> ~16% in range.
// ---------------------------------------------------------------------------
__global__ __launch_bounds__(256) void detect_dtype(const u16* __restrict__ emb,
                                                    int* __restrict__ flag) {
  __shared__ int cnt;
  int tid = threadIdx.x;
  if (tid == 0) cnt = 0;
  __syncthreads();
  int sane = 0;
  for (int i = tid; i < 1024; i += 256) {
    u16 v = emb[2 * i];
    int ex = (v >> 7) & 0xff;
    sane += (ex >= 87 && ex <= 127) ? 1 : 0;
  }
  atomicAdd(&cnt, sane);
  __syncthreads();
  if (tid == 0) *flag = (cnt < 512) ? 1 : 0;  // 1 = fp32, 0 = bf16
}

// ---------------------------------------------------------------------------
// Transpose W [K x N] cols [ncol0, ncol0+gridDim.y*64) -> WT [(n-ncol0)][k],
// optionally folding LoRA: + scale * sum_r la[h][r]*lb[r][f]. Dual dtype in,
// bf16 out. grid (K/64, cols/64, E), block 256.
// ---------------------------------------------------------------------------
__global__ __launch_bounds__(256) void transpose_lora(
    const void* __restrict__ W, u16* __restrict__ WT,
    const void* __restrict__ la, const void* __restrict__ lb,
    int K, int N, int hasLora, int ncol0, const int* __restrict__ flag) {
  int isf32 = *flag;
  int tk = blockIdx.x * 64;
  int tn = ncol0 + blockIdx.y * 64;      // global col base
  int e  = blockIdx.z;
  __shared__ alignas(16) u16 tile[64][72];
  int tid = threadIdx.x;
  int row = tid >> 2, c0l = (tid & 3) * 16;
  size_t src = (size_t)e * K * N + (size_t)(tk + row) * N + tn + c0l;
  u16 tmp[16];
  if (isf32) {
    const float* Wf = (const float*)W;
#pragma unroll
    for (int j = 0; j < 4; ++j) {
      float4 f = *(const float4*)(Wf + src + j * 4);
      tmp[j * 4 + 0] = f2bf(f.x); tmp[j * 4 + 1] = f2bf(f.y);
      tmp[j * 4 + 2] = f2bf(f.z); tmp[j * 4 + 3] = f2bf(f.w);
    }
  } else {
    const u16* Wh = (const u16*)W;
    *(uint4*)&tmp[0] = *(const uint4*)(Wh + src);
    *(uint4*)&tmp[8] = *(const uint4*)(Wh + src + 8);
  }
  *(uint4*)&tile[row][c0l] = *(uint4*)&tmp[0];
  *(uint4*)&tile[row][c0l + 8] = *(uint4*)&tmp[8];
  __syncthreads();
  int f = tid >> 2;            // local out-row (N dim)
  int h0 = (tid & 3) * 16;     // local out-col chunk (K dim)
  float lbv[4];
  if (hasLora) {
#pragma unroll
    for (int r = 0; r < 4; ++r)
      lbv[r] = lde(lb, (size_t)e * 4 * N + (size_t)r * N + tn + f, isf32);
  }
  u16 outv[16];
#pragma unroll
  for (int i = 0; i < 16; ++i) {
    float x = bf2f(tile[h0 + i][f]);
    if (hasLora) {
      size_t lbase = ((size_t)e * K + tk + h0 + i) * 4;
      float s = 0.f;
#pragma unroll
      for (int r = 0; r < 4; ++r) s += lde(la, lbase + r, isf32) * lbv[r];
      x += LSCALE * s;
    }
    outv[i] = f2bf(x);
  }
  u16* dst = WT + (size_t)e * K * N + (size_t)(blockIdx.y * 64 + f) * K + tk + h0;
  *(uint4*)dst = *(uint4*)&outv[0];
  *(uint4*)(dst + 8) = *(uint4*)&outv[8];
}

// ---------------------------------------------------------------------------
// Embedding gather + gate logits + softmax + top-2 renormalized routing.
// grid: 2048 (one token per block), block 256. Dual dtype.
// ---------------------------------------------------------------------------
__global__ __launch_bounds__(256) void embed_gate(
    const int* __restrict__ x, const void* __restrict__ emb,
    const void* __restrict__ gw, const void* __restrict__ gb,
    u16* __restrict__ h_bf, float* __restrict__ routw,
    const int* __restrict__ flag) {
  int isf32 = *flag;
  int t = blockIdx.x, tid = threadIdx.x;
  __shared__ float hs[HDIM];
  __shared__ float gl[NEXP];
  int idx = x[t];
  if (isf32) {
    const float* er = (const float*)emb + (size_t)idx * HDIM;
    float4 f = ((const float4*)er)[tid];
    u16 h4[4] = { f2bf(f.x), f2bf(f.y), f2bf(f.z), f2bf(f.w) };
    ((uint2*)(h_bf + (size_t)t * HDIM))[tid] = *(uint2*)h4;
    hs[tid * 4 + 0] = f.x; hs[tid * 4 + 1] = f.y;
    hs[tid * 4 + 2] = f.z; hs[tid * 4 + 3] = f.w;
  } else {
    uint2 v = ((const uint2*)((const u16*)emb + (size_t)idx * HDIM))[tid];
    ((uint2*)(h_bf + (size_t)t * HDIM))[tid] = v;
    hs[tid * 4 + 0] = bf2f((u16)(v.x & 0xffffu));
    hs[tid * 4 + 1] = bf2f((u16)(v.x >> 16));
    hs[tid * 4 + 2] = bf2f((u16)(v.y & 0xffffu));
    hs[tid * 4 + 3] = bf2f((u16)(v.y >> 16));
  }
  __syncthreads();
  int wid = tid >> 6, lane = tid & 63;
  int c0 = wid * 2, c1 = c0 + 1;
  float p0 = 0.f, p1 = 0.f;
  for (int i = lane; i < HDIM; i += 64) {
    float hv = hs[i];
    p0 += hv * lde(gw, (size_t)i * 8 + c0, isf32);
    p1 += hv * lde(gw, (size_t)i * 8 + c1, isf32);
  }
#pragma unroll
  for (int off = 32; off; off >>= 1) {
    p0 += __shfl_down(p0, off, 64);
    p1 += __shfl_down(p1, off, 64);
  }
  if (lane == 0) { gl[c0] = p0 + lde(gb, c0, isf32); gl[c1] = p1 + lde(gb, c1, isf32); }
  __syncthreads();
  if (tid == 0) {
    float mx = gl[0];
#pragma unroll
    for (int e = 1; e < NEXP; ++e) mx = fmaxf(mx, gl[e]);
    float pe[NEXP];
#pragma unroll
    for (int e = 0; e < NEXP; ++e) pe[e] = expf(gl[e] - mx);
    int i1 = 0;
#pragma unroll
    for (int e = 1; e < NEXP; ++e) if (pe[e] > pe[i1]) i1 = e;
    int i2 = (i1 == 0) ? 1 : 0;
#pragma unroll
    for (int e = 0; e < NEXP; ++e) if (e != i1 && pe[e] > pe[i2]) i2 = e;
    float s2 = pe[i1] + pe[i2];
    float* rw = routw + (size_t)t * 8;
#pragma unroll
    for (int e = 0; e < NEXP; ++e) rw[e] = 0.f;
    rw[i1] = pe[i1] / s2;
    rw[i2] = pe[i2] / s2;
  }
}

// ---------------------------------------------------------------------------
// Pyramid cache: per-expert top-(n/2) by importance via 4-level radix select
// on order-preserving 32-bit keys (fp32 bits or bf16<<16; all values >= 0),
// jax tie rule (value desc, index asc). Mean-pool + value-LoRA (linear) +
// expert bias -> ec[e][f].  grid: 8, block 256. Dual dtype.
// ---------------------------------------------------------------------------
__global__ __launch_bounds__(256) void cache_compress(
    const void* __restrict__ cv, const void* __restrict__ imp,
    const void* __restrict__ cla, const void* __restrict__ clb,
    const void* __restrict__ eb, float* __restrict__ ec,
    const int* __restrict__ flag) {
  int isf32 = *flag;
  int e = blockIdx.x, tid = threadIdx.x;
  int n = 2048 - 128 * e, k = n >> 1;
  __shared__ unsigned keys[2048];
  __shared__ int hist[256];
  __shared__ short list[1024];
  __shared__ unsigned s_prefix;
  __shared__ int s_above;
  __shared__ float tmp4[4];
  for (int i = tid; i < n; i += 256) {
    if (isf32) {
      union { float f; unsigned u; } c; c.f = ((const float*)imp)[e * 2048 + i];
      keys[i] = c.u;
    } else {
      keys[i] = ((unsigned)((const u16*)imp)[e * 2048 + i]) << 16;
    }
  }
  __syncthreads();
  unsigned prefix = 0; int above = 0;
  for (int level = 3; level >= 0; --level) {
    hist[tid] = 0;
    __syncthreads();
    for (int i = tid; i < n; i += 256) {
      unsigned kk = keys[i];
      bool m = (level == 3) || ((kk >> ((level + 1) * 8)) == prefix);
      if (m) atomicAdd(&hist[(kk >> (level * 8)) & 255], 1);
    }
    __syncthreads();
    if (tid == 0) {
      int cum = 0, b = 255;
      for (; b > 0; --b) { int h = hist[b]; if (above + cum + h >= k) break; cum += h; }
      s_above = above + cum;
      s_prefix = (prefix << 8) | (unsigned)b;
    }
    __syncthreads();
    prefix = s_prefix; above = s_above;
  }
  // prefix = exact pivot key; above = # keys strictly greater
  if (tid == 0) {
    int need = k - above, c = 0;
    for (int i = 0; i < n; ++i) {
      unsigned kk = keys[i];
      if (kk > prefix) list[c++] = (short)i;
      else if (kk == prefix && need > 0) { list[c++] = (short)i; --need; }
    }
  }
  if (tid < 4) tmp4[tid] = 0.f;
  __syncthreads();
  int f0 = tid * 4;
  float a0 = 0.f, a1 = 0.f, a2 = 0.f, a3 = 0.f;
  if (isf32) {
    const float* cvf = (const float*)cv;
#pragma unroll 2
    for (int j = 0; j < k; ++j) {
      int row = list[j];
      float4 vv = *(const float4*)(cvf + ((size_t)e * 2048 + row) * HDIM + f0);
      a0 += vv.x; a1 += vv.y; a2 += vv.z; a3 += vv.w;
    }
  } else {
    const u16* cvh = (const u16*)cv;
#pragma unroll 2
    for (int j = 0; j < k; ++j) {
      int row = list[j];
      uint2 vv = *(const uint2*)(cvh + ((size_t)e * 2048 + row) * HDIM + f0);
      a0 += bf2f((u16)(vv.x & 0xffffu));
      a1 += bf2f((u16)(vv.x >> 16));
      a2 += bf2f((u16)(vv.y & 0xffffu));
      a3 += bf2f((u16)(vv.y >> 16));
    }
  }
  float inv = 1.f / (float)k;
  float m[4] = { a0 * inv, a1 * inv, a2 * inv, a3 * inv };
#pragma unroll
  for (int r = 0; r < 4; ++r) {
    float pr = 0.f;
#pragma unroll
    for (int i = 0; i < 4; ++i)
      pr += m[i] * lde(cla, ((size_t)e * HDIM + f0 + i) * 4 + r, isf32);
    atomicAdd(&tmp4[r], pr);
  }
  __syncthreads();
#pragma unroll
  for (int i = 0; i < 4; ++i) {
    int f = f0 + i;
    float add = 0.f;
#pragma unroll
    for (int r = 0; r < 4; ++r)
      add += tmp4[r] * lde(clb, (size_t)e * 4 * HDIM + r * HDIM + f, isf32);
    ec[e * HDIM + f] = m[i] + LSCALE * add + lde(eb, (size_t)e * HDIM + f, isf32);
  }
}

// ---------------------------------------------------------------------------
// Expert GEMMs (dense over 8 experts) with routed-weighted accumulate.
// All operands are internal bf16 ws buffers. BM=64, BN=128, BK=32;
// grid (32, 8), block 256. Register-mediated staging.
// ---------------------------------------------------------------------------
__global__ __launch_bounds__(256) void gemm_experts(
    const u16* __restrict__ A, const u16* __restrict__ Bt,
    const float* __restrict__ routw, const float* __restrict__ ec,
    u16* __restrict__ outh) {
  const int K = HDIM;
  int m0 = blockIdx.x * 64, n0 = blockIdx.y * 128;
  __shared__ alignas(16) u16 As[64 * 32];
  __shared__ alignas(16) u16 Bs[128 * 32];
  int tid = threadIdx.x, lane = tid & 63, wid = tid >> 6;
  int wm = wid >> 1, wn = wid & 1;
  int q = lane >> 4, lr = lane & 15;
  int r0 = tid >> 2, c8 = tid & 3;
  const u16* Ag = A + (size_t)(m0 + r0) * K + c8 * 8;
  u16* AsW = As + r0 * 32 + c8 * 8;
  u16* BsW = Bs + r0 * 32 + c8 * 8;
  f32x4 fin[2][4];
#pragma unroll
  for (int mi = 0; mi < 2; ++mi)
#pragma unroll
    for (int ni = 0; ni < 4; ++ni) fin[mi][ni] = (f32x4){0.f, 0.f, 0.f, 0.f};

  for (int e = 0; e < NEXP; ++e) {
    const u16* Bg = Bt + (size_t)e * K * HDIM + (size_t)(n0 + r0) * K + c8 * 8;
    f32x4 acc[2][4];
#pragma unroll
    for (int mi = 0; mi < 2; ++mi)
#pragma unroll
      for (int ni = 0; ni < 4; ++ni) acc[mi][ni] = (f32x4){0.f, 0.f, 0.f, 0.f};
    for (int kt = 0; kt < K / 32; ++kt) {
      uint4 av  = *(const uint4*)(Ag + kt * 32);
      uint4 bv0 = *(const uint4*)(Bg + kt * 32);
      uint4 bv1 = *(const uint4*)(Bg + (size_t)64 * K + kt * 32);
      __syncthreads();
      *(uint4*)AsW = av;
      *(uint4*)BsW = bv0;
      *(uint4*)(BsW + 2048) = bv1;
      __syncthreads();
      bf16x8 af[2], bfr[4];
#pragma unroll
      for (int mi = 0; mi < 2; ++mi)
        af[mi] = *(const bf16x8*)(As + (wm * 32 + mi * 16 + lr) * 32 + q * 8);
#pragma unroll
      for (int ni = 0; ni < 4; ++ni)
        bfr[ni] = *(const bf16x8*)(Bs + (wn * 64 + ni * 16 + lr) * 32 + q * 8);
#pragma unroll
      for (int mi = 0; mi < 2; ++mi)
#pragma unroll
        for (int ni = 0; ni < 4; ++ni)
          acc[mi][ni] = __builtin_amdgcn_mfma_f32_16x16x32_bf16(af[mi], bfr[ni], acc[mi][ni], 0, 0, 0);
    }
    float wr[2][4];
#pragma unroll
    for (int mi = 0; mi < 2; ++mi)
#pragma unroll
      for (int r = 0; r < 4; ++r) {
        int row = m0 + wm * 32 + mi * 16 + q * 4 + r;
        wr[mi][r] = routw[(size_t)row * 8 + e];
      }
#pragma unroll
    for (int ni = 0; ni < 4; ++ni) {
      float ecv = ec[e * HDIM + n0 + wn * 64 + ni * 16 + lr];
#pragma unroll
      for (int mi = 0; mi < 2; ++mi)
#pragma unroll
        for (int r = 0; r < 4; ++r)
          fin[mi][ni][r] += wr[mi][r] * (acc[mi][ni][r] + ecv);
    }
  }
#pragma unroll
  for (int mi = 0; mi < 2; ++mi)
#pragma unroll
    for (int ni = 0; ni < 4; ++ni) {
      int col = n0 + wn * 64 + ni * 16 + lr;
#pragma unroll
      for (int r = 0; r < 4; ++r) {
        int row = m0 + wm * 32 + mi * 16 + q * 4 + r;
        outh[(size_t)row * HDIM + col] = f2bf(fin[mi][ni][r]);
      }
    }
}

// ---------------------------------------------------------------------------
// Vocab GEMM over a column chunk: out[t][n0base+c] = (outh @ vwT_chunk) + vb.
// Output dtype per flag. BM=BN=128, BK=32; block 256.
// ---------------------------------------------------------------------------
__global__ __launch_bounds__(256) void gemm_vocab(
    const u16* __restrict__ A, const u16* __restrict__ Bt,
    const void* __restrict__ bias, void* __restrict__ outp,
    int n0base, const int* __restrict__ flag) {
  int isf32 = *flag;
  const int K = HDIM, N = VDIM;
  int m0 = blockIdx.x * 128, n0l = blockIdx.y * 128;
  __shared__ alignas(16) u16 As[128 * 32];
  __shared__ alignas(16) u16 Bs[128 * 32];
  int tid = threadIdx.x, lane = tid & 63, wid = tid >> 6;
  int wm = wid >> 1, wn = wid & 1;
  int q = lane >> 4, lr = lane & 15;
  int r0 = tid >> 2, c8 = tid & 3;
  const u16* Ag0 = A + (size_t)(m0 + r0) * K + c8 * 8;
  const u16* Ag1 = A + (size_t)(m0 + 64 + r0) * K + c8 * 8;
  const u16* Bg0 = Bt + (size_t)(n0l + r0) * K + c8 * 8;
  const u16* Bg1 = Bt + (size_t)(n0l + 64 + r0) * K + c8 * 8;
  u16* AsW = As + r0 * 32 + c8 * 8;
  u16* BsW = Bs + r0 * 32 + c8 * 8;
  f32x4 acc[4][4];
#pragma unroll
  for (int mi = 0; mi < 4; ++mi)
#pragma unroll
    for (int ni = 0; ni < 4; ++ni) acc[mi][ni] = (f32x4){0.f, 0.f, 0.f, 0.f};

  for (int kt = 0; kt < K / 32; ++kt) {
    uint4 av0 = *(const uint4*)(Ag0 + kt * 32);
    uint4 av1 = *(const uint4*)(Ag1 + kt * 32);
    uint4 bv0 = *(const uint4*)(Bg0 + kt * 32);
    uint4 bv1 = *(const uint4*)(Bg1 + kt * 32);
    __syncthreads();
    *(uint4*)AsW = av0;
    *(uint4*)(AsW + 2048) = av1;
    *(uint4*)BsW = bv0;
    *(uint4*)(BsW + 2048) = bv1;
    __syncthreads();
    bf16x8 af[4], bfr[4];
#pragma unroll
    for (int mi = 0; mi < 4; ++mi)
      af[mi] = *(const bf16x8*)(As + (wm * 64 + mi * 16 + lr) * 32 + q * 8);
#pragma unroll
    for (int ni = 0; ni < 4; ++ni)
      bfr[ni] = *(const bf16x8*)(Bs + (wn * 64 + ni * 16 + lr) * 32 + q * 8);
#pragma unroll
    for (int mi = 0; mi < 4; ++mi)
#pragma unroll
      for (int ni = 0; ni < 4; ++ni)
        acc[mi][ni] = __builtin_amdgcn_mfma_f32_16x16x32_bf16(af[mi], bfr[ni], acc[mi][ni], 0, 0, 0);
  }
#pragma unroll
  for (int ni = 0; ni < 4; ++ni) {
    int col = n0base + n0l + wn * 64 + ni * 16 + lr;
    float vb = lde(bias, col, isf32);
#pragma unroll
    for (int mi = 0; mi < 4; ++mi) {
#pragma unroll
      for (int r = 0; r < 4; ++r) {
        int row = m0 + wm * 64 + mi * 16 + q * 4 + r;
        float val = acc[mi][ni][r] + vb;
        if (isf32) ((float*)outp)[(size_t)row * N + col] = val;
        else       ((u16*)outp)[(size_t)row * N + col] = f2bf(val);
      }
    }
  }
}

// ---------------------------------------------------------------------------
extern "C" void kernel_launch(void* const* d_in, const int* in_sizes, int n_in,
                              void* d_out, int out_size, void* d_ws, size_t ws_size,
                              hipStream_t stream) {
  const int*  x    = (const int*)d_in[0];
  const void* emb  = d_in[1];
  const void* gw   = d_in[2];
  const void* gb   = d_in[3];
  const void* ew   = d_in[4];
  const void* eb   = d_in[5];
  const void* ela  = d_in[6];
  const void* elb  = d_in[7];
  const void* cv   = d_in[8];
  const void* imp  = d_in[9];
  const void* cla  = d_in[10];
  const void* clb  = d_in[11];
  const void* vw   = d_in[12];
  const void* vb   = d_in[13];

  char* ws = (char*)d_ws;
  u16*   WeffT = (u16*)(ws);                 // 8x1024x1024 bf16 = 16,777,216 B
  u16*   h_bf  = (u16*)(ws + 16777216);      // 2048x1024 bf16  =  4,194,304 B
  u16*   outh  = (u16*)(ws + 20971520);      // 2048x1024 bf16  =  4,194,304 B
  float* routw = (float*)(ws + 25165824);    // 2048x8 f32      =     65,536 B
  float* ec    = (float*)(ws + 25231360);    // 8x1024 f32      =     32,768 B
  int*   flag  = (int*)(ws + 25264128);      // 4 B
  u16*   chunk = (u16*)(ws + 25264144);      // vwT chunk, sized from ws_size

  // chunk columns of vocab_w transposed at a time (128-granular)
  long long avail = (long long)ws_size - 25264144LL;
  long long cc = (avail > 0) ? (avail / (HDIM * 2)) : 0;
  cc &= ~127LL;
  if (cc > VDIM) cc = VDIM;
  if (cc < 128) cc = 128;  // last resort; assumes ws covers the fixed region
  int chunkcols = (int)cc;

  detect_dtype<<<dim3(1), 256, 0, stream>>>((const u16*)emb, flag);
  // fold expert LoRA into weights + transpose -> WeffT [e][f][h]
  transpose_lora<<<dim3(HDIM / 64, HDIM / 64, NEXP), 256, 0, stream>>>(
      ew, WeffT, ela, elb, HDIM, HDIM, 1, 0, flag);
  // embedding gather + gate + top-2 routing
  embed_gate<<<dim3(NTOK), 256, 0, stream>>>(x, emb, gw, gb, h_bf, routw, flag);
  // pyramid cache compression -> ec[e][f] (includes expert bias)
  cache_compress<<<dim3(NEXP), 256, 0, stream>>>(cv, imp, cla, clb, eb, ec, flag);
  // expert GEMMs + routed weighted combine -> outh bf16
  gemm_experts<<<dim3(NTOK / 64, HDIM / 128), 256, 0, stream>>>(
      h_bf, WeffT, routw, ec, outh);
  // vocab projection in column chunks: transpose chunk then GEMM
  for (int c0 = 0; c0 < VDIM; c0 += chunkcols) {
    int nc = (VDIM - c0 < chunkcols) ? (VDIM - c0) : chunkcols;
    transpose_lora<<<dim3(HDIM / 64, nc / 64, 1), 256, 0, stream>>>(
        vw, chunk, nullptr, nullptr, HDIM, VDIM, 0, c0, flag);
    gemm_vocab<<<dim3(NTOK / 128, nc / 128), 256, 0, stream>>>(
        outh, chunk, vb, d_out, c0, flag);
  }
}